// Round 3
// baseline (988.478 us; speedup 1.0000x reference)
//
#include <hip/hip_runtime.h>
#include <math.h>

// CapsuleLayer routing on MI355X (gfx950). All fp32.
// B=64, n_nodes=2048, n_caps=32, in_C=16, out_C=32, 3 routing iterations.
// priors [64,2048,32,32] fp32 = 512 MB -> never materialized; 3 recompute
// passes over W with reduce+squash between. Round 3 change: block = 1024 thr
// covers ALL 64 batches x 32 k; grid = 256 blocks (1/CU); W is read exactly
// once per pass (round 2's grid.y=2 read it twice -> 154 us/pass at only
// 37% VALUBusy; traffic through L1/L2/LDS was the limiter).
// Per-thread tile unchanged: 2 b (same k) x 32 o fp32 accumulators (128 VGPR).

#define BATCH   64
#define NNODES  2048
#define NCAPS   32
#define INC     16
#define OUTC    32
#define NCHUNK  8                  // nodes per block
#define NBLK    (NNODES / NCHUNK)  // 256 blocks
#define THREADS 1024
#define WK_STRIDE 516              // fp32 floats per k-slice in LDS (512 + 4 pad)

template <int PASS>
__global__ __launch_bounds__(THREADS, 4) void pass_kernel(
    const float* __restrict__ xg,   // fp32 [B, NNODES, INC]
    const float* __restrict__ Wg,   // fp32 [NNODES, NCAPS, INC, OUTC]
    const float* __restrict__ outv, // fp32 [B, NCAPS, OUTC] (PASS>=1)
    float* __restrict__ logits,     // fp32 [B, NNODES, NCAPS]
    float* __restrict__ partial)    // fp32 [NBLK, B, NCAPS, OUTC]
{
    __shared__ float w_lds[NCAPS * WK_STRIDE];      // 66048 B
    __shared__ float x_lds[BATCH][INC + 1];         //  4352 B
    __shared__ float delta_lds[BATCH][NCAPS + 1];   //  8448 B

    const int t   = threadIdx.x;
    const int nb  = blockIdx.x;          // node-chunk
    const int k   = t >> 5;              // 0..31 (capsule)
    const int bq  = t & 31;
    const int bl0 = bq * 2;              // 0..62
    const int bl1 = bq * 2 + 1;          // 1..63

    float acc0[OUTC], acc1[OUTC];
#pragma unroll
    for (int o = 0; o < OUTC; ++o) { acc0[o] = 0.f; acc1[o] = 0.f; }

    float outr0[OUTC], outr1[OUTC];
    if constexpr (PASS >= 1) {
        const float4* o0 = (const float4*)&outv[(bl0 * NCAPS + k) * OUTC];
        const float4* o1 = (const float4*)&outv[(bl1 * NCAPS + k) * OUTC];
#pragma unroll
        for (int q = 0; q < OUTC / 4; ++q) {
            float4 a = o0[q]; float4 b = o1[q];
            outr0[4*q+0]=a.x; outr0[4*q+1]=a.y; outr0[4*q+2]=a.z; outr0[4*q+3]=a.w;
            outr1[4*q+0]=b.x; outr1[4*q+1]=b.y; outr1[4*q+2]=b.z; outr1[4*q+3]=b.w;
        }
    }

    for (int j = 0; j < NCHUNK; ++j) {
        const int n = nb * NCHUNK + j;
        __syncthreads();   // protect LDS from previous iteration's readers
        // ---- stage W[n]: 16384 fp32 -> LDS (16B loads, 16B LDS stores) ----
        {
            const float4* src = (const float4*)(Wg + (size_t)n * (NCAPS * INC * OUTC));
#pragma unroll
            for (int r = 0; r < (NCAPS * INC * OUTC / 4) / THREADS; ++r) {  // 4 iters
                int idx4 = t + r * THREADS;
                float4 v = src[idx4];
                int e   = idx4 * 4;
                int kk  = e >> 9;        // /512
                int rem = e & 511;
                *(float4*)&w_lds[kk * WK_STRIDE + rem] = v;   // both 16B-aligned
            }
        }
        // ---- stage x rows: 64 b x 16 i (exactly 1024 elements) ----
        {
            int bl = t >> 4;             // 0..63
            int i  = t & 15;
            x_lds[bl][i] = xg[((size_t)bl * NNODES + n) * INC + i];
        }
        __syncthreads();

        if constexpr (PASS == 0) {
            // uniform probs: accumulate priors; scale by 1/32 at the end
#pragma unroll
            for (int i = 0; i < INC; ++i) {
                float xa = x_lds[bl0][i];
                float xb = x_lds[bl1][i];
                const float* wrow = &w_lds[k * WK_STRIDE + i * OUTC];
#pragma unroll
                for (int o = 0; o < OUTC; ++o) {
                    float w = wrow[o];
                    acc0[o] = fmaf(xa, w, acc0[o]);
                    acc1[o] = fmaf(xb, w, acc1[o]);
                }
            }
        } else {
            float pr0[OUTC], pr1[OUTC];
#pragma unroll
            for (int o = 0; o < OUTC; ++o) { pr0[o] = 0.f; pr1[o] = 0.f; }
#pragma unroll
            for (int i = 0; i < INC; ++i) {
                float xa = x_lds[bl0][i];
                float xb = x_lds[bl1][i];
                const float* wrow = &w_lds[k * WK_STRIDE + i * OUTC];
#pragma unroll
                for (int o = 0; o < OUTC; ++o) {
                    float w = wrow[o];
                    pr0[o] = fmaf(xa, w, pr0[o]);
                    pr1[o] = fmaf(xb, w, pr1[o]);
                }
            }
            // delta = prior . out
            float d0 = 0.f, d1 = 0.f;
#pragma unroll
            for (int o = 0; o < OUTC; ++o) {
                d0 = fmaf(pr0[o], outr0[o], d0);
                d1 = fmaf(pr1[o], outr1[o], d1);
            }
            float l0 = d0, l1 = d1;
            const size_t li0 = ((size_t)bl0 * NNODES + n) * NCAPS + k;
            const size_t li1 = ((size_t)bl1 * NNODES + n) * NCAPS + k;
            if constexpr (PASS == 2) {
                l0 += logits[li0];
                l1 += logits[li1];
            } else {
                logits[li0] = d0;
                logits[li1] = d1;
            }
            delta_lds[bl0][k] = l0;
            delta_lds[bl1][k] = l1;
            __syncthreads();
            // softmax over k (each thread recomputes for its two b rows)
            float m0 = -1e30f, m1 = -1e30f;
#pragma unroll
            for (int kk = 0; kk < NCAPS; ++kk) {
                m0 = fmaxf(m0, delta_lds[bl0][kk]);
                m1 = fmaxf(m1, delta_lds[bl1][kk]);
            }
            float s0 = 0.f, s1 = 0.f;
#pragma unroll
            for (int kk = 0; kk < NCAPS; ++kk) {
                s0 += __expf(delta_lds[bl0][kk] - m0);
                s1 += __expf(delta_lds[bl1][kk] - m1);
            }
            float p0 = __expf(l0 - m0) / s0;
            float p1 = __expf(l1 - m1) / s1;
#pragma unroll
            for (int o = 0; o < OUTC; ++o) {
                acc0[o] = fmaf(p0, pr0[o], acc0[o]);
                acc1[o] = fmaf(p1, pr1[o], acc1[o]);
            }
        }
    }

    const float scale = (PASS == 0) ? (1.f / NCAPS) : 1.f;
    float4* p0 = (float4*)&partial[(((size_t)nb * BATCH + bl0) * NCAPS + k) * OUTC];
    float4* p1 = (float4*)&partial[(((size_t)nb * BATCH + bl1) * NCAPS + k) * OUTC];
#pragma unroll
    for (int q = 0; q < OUTC / 4; ++q) {
        float4 v0, v1;
        v0.x = acc0[4*q+0] * scale; v0.y = acc0[4*q+1] * scale;
        v0.z = acc0[4*q+2] * scale; v0.w = acc0[4*q+3] * scale;
        v1.x = acc1[4*q+0] * scale; v1.y = acc1[4*q+1] * scale;
        v1.z = acc1[4*q+2] * scale; v1.w = acc1[4*q+3] * scale;
        p0[q] = v0;
        p1[q] = v1;
    }
}

// Reduce partials over node-chunks, then squash within each (b,k) 32-vector.
// tid = b*1024 + k*32 + o; the 32 lanes of a (b,k) group are contiguous, so a
// shuffle-xor butterfly over masks 1..16 sums ||v||^2 within the group.
__global__ __launch_bounds__(256) void reduce_squash(
    const float* __restrict__ partial,
    float* __restrict__ outf)
{
    const int tid = blockIdx.x * 256 + threadIdx.x;   // 0..65535
    float v = 0.f;
    for (int nb = 0; nb < NBLK; ++nb)
        v += partial[(size_t)nb * (BATCH * NCAPS * OUTC) + tid];
    float sq = v * v;
#pragma unroll
    for (int off = 1; off < 32; off <<= 1)
        sq += __shfl_xor(sq, off);
    // squash: (sq/(1+sq)) * v/sqrt(sq)
    float coef = sq / ((1.f + sq) * sqrtf(sq));
    outf[tid] = v * coef;
}

extern "C" void kernel_launch(void* const* d_in, const int* in_sizes, int n_in,
                              void* d_out, int out_size, void* d_ws, size_t ws_size,
                              hipStream_t stream)
{
    const float* xg = (const float*)d_in[0];   // fp32 x
    const float* Wg = (const float*)d_in[1];   // fp32 route_weights
    float* outp = (float*)d_out;               // fp32 output [64,1,32,32]

    char* ws = (char*)d_ws;
    float* partial = (float*)ws;                                          // 64 MiB
    float* logits  = (float*)(ws + (size_t)NBLK * BATCH * NCAPS * OUTC * sizeof(float));   // 16 MiB
    float* outv    = (float*)(ws + (size_t)NBLK * BATCH * NCAPS * OUTC * sizeof(float)
                                 + (size_t)BATCH * NNODES * NCAPS * sizeof(float));        // 256 KiB

    const int rblocks = BATCH * NCAPS * OUTC / 256;  // 256

    // iter 0
    pass_kernel<0><<<NBLK, THREADS, 0, stream>>>(xg, Wg, nullptr, logits, partial);
    reduce_squash<<<rblocks, 256, 0, stream>>>(partial, outv);
    // iter 1
    pass_kernel<1><<<NBLK, THREADS, 0, stream>>>(xg, Wg, outv, logits, partial);
    reduce_squash<<<rblocks, 256, 0, stream>>>(partial, outv);
    // iter 2
    pass_kernel<2><<<NBLK, THREADS, 0, stream>>>(xg, Wg, outv, logits, partial);
    reduce_squash<<<rblocks, 256, 0, stream>>>(partial, outp);
}

// Round 4
// 499.153 us; speedup vs baseline: 1.9803x; 1.9803x over previous
//
#include <hip/hip_runtime.h>
#include <math.h>

// CapsuleLayer routing on MI355X (gfx950). fp32 in/out.
// B=64, n=2048, k=32, in_C=16, out_C=32, 3 routing iterations.
//
// Fast path (needs ~341 MiB ws): materialize priors in bf16 once via MFMA
// (32x32x16: M=32 batch, N=32 out_C, K=16 in_C -- exact shape match), then
// iterations 1/2 are pure streaming passes over bf16 priors (no GEMM
// recompute). Falls back to the round-2 fp32 recompute path if ws is small.
//
// Round-3 lesson: >=64 fp32 accumulators/thread forbids 1024-thr blocks
// (VGPR cap 128 at 16 waves/block -> spill storm, WRITE_SIZE 545 MB). All
// kernels here keep blocks at <=512 threads.

#define BATCH 64
#define NN    2048
#define NK    32
#define NI    16
#define NO    32

typedef __bf16 bf16x8 __attribute__((ext_vector_type(8)));
typedef float  f32x16 __attribute__((ext_vector_type(16)));

__device__ __forceinline__ unsigned short f2bf(float f) {
    unsigned int x = __float_as_uint(f);
    unsigned int lsb = (x >> 16) & 1u;
    x += 0x7fffu + lsb;                 // RNE
    return (unsigned short)(x >> 16);
}
__device__ __forceinline__ float bflo(unsigned int u) { return __uint_as_float(u << 16); }
__device__ __forceinline__ float bfhi(unsigned int u) { return __uint_as_float(u & 0xffff0000u); }

// ---------------- fast path ----------------

// x [b][n][i] fp32 -> xT [n][b][i] bf16
__global__ __launch_bounds__(256) void xt_kernel(const float* __restrict__ xg,
                                                 unsigned short* __restrict__ xT) {
    int id = blockIdx.x * 256 + threadIdx.x;      // 524288 = 64*2048*4
    int b = id >> 13;                             // /(2048*4)
    int rem = id & 8191;
    int n = rem >> 2;
    int i4 = rem & 3;
    float4 v = *(const float4*)(xg + ((size_t)b * NN + n) * NI + i4 * 4);
    ushort4 o;
    o.x = f2bf(v.x); o.y = f2bf(v.y); o.z = f2bf(v.z); o.w = f2bf(v.w);
    *(ushort4*)(xT + ((size_t)n * BATCH + b) * NI + i4 * 4) = o;
}

// One wave per (chunk c of 16 nodes, capsule k). 512 blocks x 8 waves.
// Computes priors[n][k][64b][32o] bf16 + s0 partial (scaled 1/32).
__global__ __launch_bounds__(512) void k1_kernel(
    const unsigned short* __restrict__ xT,   // bf16 [n][b][i]
    const float* __restrict__ Wg,            // fp32 [n][k][i][o]
    unsigned short* __restrict__ priors,     // bf16 [n][k][b][o]
    float* __restrict__ partial)             // fp32 [128][b][k][o]
{
    const int w    = threadIdx.x >> 6;
    const int lane = threadIdx.x & 63;
    const int task = blockIdx.x * 8 + w;     // 4096 tasks
    const int k = task & 31;
    const int c = task >> 5;                 // 0..127
    const int o = lane & 31;
    const int h = lane >> 5;                 // half: A rows b / b+32 split is separate

    float s0a[16], s0b[16];
#pragma unroll
    for (int r = 0; r < 16; ++r) { s0a[r] = 0.f; s0b[r] = 0.f; }

    for (int jj = 0; jj < 16; ++jj) {
        const int n = c * 16 + jj;
        // A-frags: A[m=lane&31][kdim = h*8 + j] from xT[n][b][i]
        const bf16x8 a0 = *(const bf16x8*)(xT + (size_t)n * (BATCH * NI) + (lane & 31) * NI + h * 8);
        const bf16x8 a1 = *(const bf16x8*)(xT + (size_t)n * (BATCH * NI) + ((lane & 31) + 32) * NI + h * 8);
        // B-frag: B[kdim = h*8 + j][ncol = lane&31] from W[n][k][i][o]
        const float* wp = Wg + ((size_t)n * NK + k) * (NI * NO) + (h * 8) * NO + o;
        union { unsigned short u[8]; bf16x8 v; } bu;
#pragma unroll
        for (int j = 0; j < 8; ++j) bu.u[j] = f2bf(wp[j * NO]);

        f32x16 c0, c1;
#pragma unroll
        for (int r = 0; r < 16; ++r) { c0[r] = 0.f; c1[r] = 0.f; }
        c0 = __builtin_amdgcn_mfma_f32_32x32x16_bf16(a0, bu.v, c0, 0, 0, 0);
        c1 = __builtin_amdgcn_mfma_f32_32x32x16_bf16(a1, bu.v, c1, 0, 0, 0);

        unsigned short* pp = priors + (((size_t)n * NK + k) * BATCH) * NO + o;
#pragma unroll
        for (int r = 0; r < 16; ++r) {
            int b = (r & 3) + 8 * (r >> 2) + 4 * h;      // C/D row mapping (m74/m101)
            pp[b * NO] = f2bf(c0[r]);
            pp[(b + 32) * NO] = f2bf(c1[r]);
            s0a[r] += c0[r];
            s0b[r] += c1[r];
        }
    }
    // partial [c][b][k][o], scale 1/32
    float* q = partial + (size_t)c * (BATCH * NK * NO) + k * NO + o;
#pragma unroll
    for (int r = 0; r < 16; ++r) {
        int b = (r & 3) + 8 * (r >> 2) + 4 * h;
        q[(size_t)b * (NK * NO)] = s0a[r] * (1.f / 32.f);
        q[(size_t)(b + 32) * (NK * NO)] = s0b[r] * (1.f / 32.f);
    }
}

// Iterations 1 and 2: stream priors, delta-dot vs out (bf16), cooperative
// softmax over k, accumulate s. Block 512 thr = 32 k x 16 b-pairs (32 b);
// grid (256 chunks x 2 b-groups).
template <int PASS>   // 1 or 2
__global__ __launch_bounds__(512) void k23_kernel(
    const unsigned short* __restrict__ priors,  // bf16 [n][k][b][o]
    const unsigned short* __restrict__ outvb,   // bf16 [b][k][o]  (current out)
    float* __restrict__ logits0,                // fp32 [n][k][b]
    float* __restrict__ partial)                // fp32 [256][b][k][o]
{
    __shared__ float delta_lds[32][33];
    __shared__ float m_lds[32], rs_lds[32];

    const int t  = threadIdx.x;
    const int k  = t >> 4;
    const int bp = t & 15;
    const int bg = blockIdx.y;
    const int c  = blockIdx.x;                 // 8 nodes per chunk
    const int bl0 = bg * 32 + 2 * bp, bl1 = bl0 + 1;
    const int bL0 = 2 * bp, bL1 = bL0 + 1;     // block-local rows

    union U16 { uint4 q[4]; unsigned u[16]; };
    U16 o0p, o1p;
    {
        const uint4* s0 = (const uint4*)(outvb + ((size_t)bl0 * NK + k) * NO);
        const uint4* s1 = (const uint4*)(outvb + ((size_t)bl1 * NK + k) * NO);
#pragma unroll
        for (int q = 0; q < 4; ++q) { o0p.q[q] = s0[q]; o1p.q[q] = s1[q]; }
    }

    float sa0[32], sa1[32];
#pragma unroll
    for (int o = 0; o < 32; ++o) { sa0[o] = 0.f; sa1[o] = 0.f; }

    for (int j = 0; j < 8; ++j) {
        const int n = c * 8 + j;
        __syncthreads();   // delta_lds reuse guard
        U16 q0, q1;
        {
            const uint4* p0 = (const uint4*)(priors + (((size_t)n * NK + k) * BATCH + bl0) * NO);
            const uint4* p1 = (const uint4*)(priors + (((size_t)n * NK + k) * BATCH + bl1) * NO);
#pragma unroll
            for (int q = 0; q < 4; ++q) { q0.q[q] = p0[q]; q1.q[q] = p1[q]; }
        }
        float d0 = 0.f, d1 = 0.f;
#pragma unroll
        for (int m = 0; m < 16; ++m) {
            d0 = fmaf(bflo(q0.u[m]), bflo(o0p.u[m]), d0);
            d0 = fmaf(bfhi(q0.u[m]), bfhi(o0p.u[m]), d0);
            d1 = fmaf(bflo(q1.u[m]), bflo(o1p.u[m]), d1);
            d1 = fmaf(bfhi(q1.u[m]), bfhi(o1p.u[m]), d1);
        }
        float l0, l1;
        float* lg = logits0 + ((size_t)n * NK + k) * BATCH + bl0;
        if constexpr (PASS == 1) {
            l0 = d0; l1 = d1;
            *(float2*)lg = make_float2(d0, d1);
        } else {
            float2 g = *(const float2*)lg;
            l0 = g.x + d0; l1 = g.y + d1;
        }
        delta_lds[bL0][k] = l0;
        delta_lds[bL1][k] = l1;
        __syncthreads();
        if (t < 32) {
            float m = -1e30f;
#pragma unroll
            for (int kk = 0; kk < 32; ++kk) m = fmaxf(m, delta_lds[t][kk]);
            float s = 0.f;
#pragma unroll
            for (int kk = 0; kk < 32; ++kk) s += __expf(delta_lds[t][kk] - m);
            m_lds[t] = m;
            rs_lds[t] = 1.f / s;
        }
        __syncthreads();
        float p0 = __expf(l0 - m_lds[bL0]) * rs_lds[bL0];
        float p1 = __expf(l1 - m_lds[bL1]) * rs_lds[bL1];
#pragma unroll
        for (int m = 0; m < 16; ++m) {
            sa0[2*m]   = fmaf(p0, bflo(q0.u[m]), sa0[2*m]);
            sa0[2*m+1] = fmaf(p0, bfhi(q0.u[m]), sa0[2*m+1]);
            sa1[2*m]   = fmaf(p1, bflo(q1.u[m]), sa1[2*m]);
            sa1[2*m+1] = fmaf(p1, bfhi(q1.u[m]), sa1[2*m+1]);
        }
    }
    float* w0 = partial + (((size_t)c * BATCH + bl0) * NK + k) * NO;
    float* w1 = partial + (((size_t)c * BATCH + bl1) * NK + k) * NO;
#pragma unroll
    for (int q = 0; q < 8; ++q) {
        *(float4*)(w0 + 4 * q) = make_float4(sa0[4*q], sa0[4*q+1], sa0[4*q+2], sa0[4*q+3]);
        *(float4*)(w1 + 4 * q) = make_float4(sa1[4*q], sa1[4*q+1], sa1[4*q+2], sa1[4*q+3]);
    }
}

// Reduce partial chunks + squash. tid = b*1024 + k*32 + o.
template <int NCH, int WRITEB>
__global__ __launch_bounds__(256) void reduce_squash_f(
    const float* __restrict__ partial,
    float* __restrict__ outf,
    unsigned short* __restrict__ outb)
{
    const int tid = blockIdx.x * 256 + threadIdx.x;
    float v = 0.f;
    for (int c = 0; c < NCH; ++c)
        v += partial[(size_t)c * (BATCH * NK * NO) + tid];
    float sq = v * v;
#pragma unroll
    for (int off = 1; off < 32; off <<= 1)
        sq += __shfl_xor(sq, off);
    float coef = sq / ((1.f + sq) * sqrtf(sq));
    float r = v * coef;
    outf[tid] = r;
    if (WRITEB) outb[tid] = f2bf(r);
}

// ---------------- legacy fallback (round-2 code, known-good 582 us) ----------------

#define LBB 32
#define LNCHUNK 8
#define LNBLK (NN / LNCHUNK)
#define LTHREADS 512
#define WK_STRIDE 516

template <int PASS>
__global__ __launch_bounds__(LTHREADS, 1) void legacy_pass(
    const float* __restrict__ xg, const float* __restrict__ Wg,
    const float* __restrict__ outv, float* __restrict__ logits,
    float* __restrict__ partial)
{
    __shared__ float w_lds[NK * WK_STRIDE];
    __shared__ float x_lds[LBB][NI + 1];
    __shared__ float delta_lds[LBB][NK + 1];
    const int t = threadIdx.x, nb = blockIdx.x, bg = blockIdx.y;
    const int b0 = bg * LBB;
    const int k = t >> 4, bq = t & 15, bl0 = bq * 2, bl1 = bq * 2 + 1;
    float acc0[NO], acc1[NO];
#pragma unroll
    for (int o = 0; o < NO; ++o) { acc0[o] = 0.f; acc1[o] = 0.f; }
    float outr0[NO], outr1[NO];
    if constexpr (PASS >= 1) {
        const float4* o0 = (const float4*)&outv[((b0 + bl0) * NK + k) * NO];
        const float4* o1 = (const float4*)&outv[((b0 + bl1) * NK + k) * NO];
#pragma unroll
        for (int q = 0; q < NO / 4; ++q) {
            float4 a = o0[q]; float4 b = o1[q];
            outr0[4*q+0]=a.x; outr0[4*q+1]=a.y; outr0[4*q+2]=a.z; outr0[4*q+3]=a.w;
            outr1[4*q+0]=b.x; outr1[4*q+1]=b.y; outr1[4*q+2]=b.z; outr1[4*q+3]=b.w;
        }
    }
    for (int j = 0; j < LNCHUNK; ++j) {
        const int n = nb * LNCHUNK + j;
        __syncthreads();
        {
            const float4* src = (const float4*)(Wg + (size_t)n * (NK * NI * NO));
#pragma unroll
            for (int r = 0; r < (NK * NI * NO / 4) / LTHREADS; ++r) {
                int idx4 = t + r * LTHREADS;
                float4 v = src[idx4];
                int e = idx4 * 4, kk = e >> 9, rem = e & 511;
                *(float4*)&w_lds[kk * WK_STRIDE + rem] = v;
            }
        }
        { int bl = t >> 4, i = t & 15;
          x_lds[bl][i] = xg[((size_t)(b0 + bl) * NN + n) * NI + i]; }
        __syncthreads();
        if constexpr (PASS == 0) {
#pragma unroll
            for (int i = 0; i < NI; ++i) {
                float xa = x_lds[bl0][i], xb = x_lds[bl1][i];
                const float* wrow = &w_lds[k * WK_STRIDE + i * NO];
#pragma unroll
                for (int o = 0; o < NO; ++o) {
                    float w = wrow[o];
                    acc0[o] = fmaf(xa, w, acc0[o]);
                    acc1[o] = fmaf(xb, w, acc1[o]);
                }
            }
        } else {
            float pr0[NO], pr1[NO];
#pragma unroll
            for (int o = 0; o < NO; ++o) { pr0[o] = 0.f; pr1[o] = 0.f; }
#pragma unroll
            for (int i = 0; i < NI; ++i) {
                float xa = x_lds[bl0][i], xb = x_lds[bl1][i];
                const float* wrow = &w_lds[k * WK_STRIDE + i * NO];
#pragma unroll
                for (int o = 0; o < NO; ++o) {
                    float w = wrow[o];
                    pr0[o] = fmaf(xa, w, pr0[o]);
                    pr1[o] = fmaf(xb, w, pr1[o]);
                }
            }
            float d0 = 0.f, d1 = 0.f;
#pragma unroll
            for (int o = 0; o < NO; ++o) {
                d0 = fmaf(pr0[o], outr0[o], d0);
                d1 = fmaf(pr1[o], outr1[o], d1);
            }
            float l0 = d0, l1 = d1;
            const size_t li0 = ((size_t)(b0 + bl0) * NN + n) * NK + k;
            const size_t li1 = ((size_t)(b0 + bl1) * NN + n) * NK + k;
            if constexpr (PASS == 2) { l0 += logits[li0]; l1 += logits[li1]; }
            else { logits[li0] = d0; logits[li1] = d1; }
            delta_lds[bl0][k] = l0; delta_lds[bl1][k] = l1;
            __syncthreads();
            float m0 = -1e30f, m1 = -1e30f;
#pragma unroll
            for (int kk = 0; kk < NK; ++kk) {
                m0 = fmaxf(m0, delta_lds[bl0][kk]);
                m1 = fmaxf(m1, delta_lds[bl1][kk]);
            }
            float s0 = 0.f, s1 = 0.f;
#pragma unroll
            for (int kk = 0; kk < NK; ++kk) {
                s0 += __expf(delta_lds[bl0][kk] - m0);
                s1 += __expf(delta_lds[bl1][kk] - m1);
            }
            float p0 = __expf(l0 - m0) / s0;
            float p1 = __expf(l1 - m1) / s1;
#pragma unroll
            for (int o = 0; o < NO; ++o) {
                acc0[o] = fmaf(p0, pr0[o], acc0[o]);
                acc1[o] = fmaf(p1, pr1[o], acc1[o]);
            }
        }
    }
    const float scale = (PASS == 0) ? (1.f / NK) : 1.f;
    float4* p0 = (float4*)&partial[(((size_t)nb * BATCH + (b0 + bl0)) * NK + k) * NO];
    float4* p1 = (float4*)&partial[(((size_t)nb * BATCH + (b0 + bl1)) * NK + k) * NO];
#pragma unroll
    for (int q = 0; q < NO / 4; ++q) {
        float4 v0, v1;
        v0.x = acc0[4*q+0]*scale; v0.y = acc0[4*q+1]*scale;
        v0.z = acc0[4*q+2]*scale; v0.w = acc0[4*q+3]*scale;
        v1.x = acc1[4*q+0]*scale; v1.y = acc1[4*q+1]*scale;
        v1.z = acc1[4*q+2]*scale; v1.w = acc1[4*q+3]*scale;
        p0[q] = v0; p1[q] = v1;
    }
}

__global__ __launch_bounds__(256) void legacy_reduce(
    const float* __restrict__ partial, float* __restrict__ outf)
{
    const int tid = blockIdx.x * 256 + threadIdx.x;
    float v = 0.f;
    for (int nb = 0; nb < LNBLK; ++nb)
        v += partial[(size_t)nb * (BATCH * NK * NO) + tid];
    float sq = v * v;
#pragma unroll
    for (int off = 1; off < 32; off <<= 1) sq += __shfl_xor(sq, off);
    float coef = sq / ((1.f + sq) * sqrtf(sq));
    outf[tid] = v * coef;
}

// ---------------- launch ----------------

extern "C" void kernel_launch(void* const* d_in, const int* in_sizes, int n_in,
                              void* d_out, int out_size, void* d_ws, size_t ws_size,
                              hipStream_t stream)
{
    const float* xg = (const float*)d_in[0];
    const float* Wg = (const float*)d_in[1];
    float* outp = (float*)d_out;
    char* ws = (char*)d_ws;

    const size_t SZ_PRIORS  = (size_t)NN * NK * BATCH * NO * 2;      // 256 MiB
    const size_t SZ_PARTIAL = (size_t)256 * BATCH * NK * NO * 4;     //  64 MiB
    const size_t SZ_LOGITS  = (size_t)NN * NK * BATCH * 4;           //  16 MiB
    const size_t SZ_XT      = (size_t)NN * BATCH * NI * 2;           //   4 MiB
    const size_t SZ_OUTV    = (size_t)BATCH * NK * NO * 4;           // 256 KiB
    const size_t SZ_OUTVB   = (size_t)BATCH * NK * NO * 2;           // 128 KiB
    const size_t NEED = SZ_PRIORS + SZ_PARTIAL + SZ_LOGITS + SZ_XT + SZ_OUTV + SZ_OUTVB;

    if (ws_size >= NEED) {
        unsigned short* priors = (unsigned short*)ws;
        float* partial = (float*)(ws + SZ_PRIORS);
        float* logits0 = (float*)(ws + SZ_PRIORS + SZ_PARTIAL);
        unsigned short* xT = (unsigned short*)(ws + SZ_PRIORS + SZ_PARTIAL + SZ_LOGITS);
        float* outv = (float*)(ws + SZ_PRIORS + SZ_PARTIAL + SZ_LOGITS + SZ_XT);
        unsigned short* outvb = (unsigned short*)(ws + SZ_PRIORS + SZ_PARTIAL + SZ_LOGITS + SZ_XT + SZ_OUTV);

        xt_kernel<<<2048, 256, 0, stream>>>(xg, xT);
        k1_kernel<<<512, 512, 0, stream>>>(xT, Wg, priors, partial);
        reduce_squash_f<128, 1><<<256, 256, 0, stream>>>(partial, outv, outvb);
        k23_kernel<1><<<dim3(256, 2), 512, 0, stream>>>(priors, outvb, logits0, partial);
        reduce_squash_f<256, 1><<<256, 256, 0, stream>>>(partial, outv, outvb);
        k23_kernel<2><<<dim3(256, 2), 512, 0, stream>>>(priors, outvb, logits0, partial);
        reduce_squash_f<256, 0><<<256, 256, 0, stream>>>(partial, outp, nullptr);
    } else {
        float* partial = (float*)ws;
        float* logits = (float*)(ws + (size_t)LNBLK * BATCH * NK * NO * 4);
        float* outv = (float*)(ws + (size_t)LNBLK * BATCH * NK * NO * 4 + (size_t)BATCH * NN * NK * 4);
        dim3 grid(LNBLK, BATCH / LBB);
        const int rblocks = BATCH * NK * NO / 256;
        legacy_pass<0><<<grid, LTHREADS, 0, stream>>>(xg, Wg, nullptr, logits, partial);
        legacy_reduce<<<rblocks, 256, 0, stream>>>(partial, outv);
        legacy_pass<1><<<grid, LTHREADS, 0, stream>>>(xg, Wg, outv, logits, partial);
        legacy_reduce<<<rblocks, 256, 0, stream>>>(partial, outv);
        legacy_pass<2><<<grid, LTHREADS, 0, stream>>>(xg, Wg, outv, logits, partial);
        legacy_reduce<<<rblocks, 256, 0, stream>>>(partial, outp);
    }
}

// Round 5
// 493.282 us; speedup vs baseline: 2.0039x; 1.0119x over previous
//
#include <hip/hip_runtime.h>
#include <math.h>

// CapsuleLayer routing on MI355X (gfx950). fp32 in/out.
// B=64, n=2048, k=32, in_C=16, out_C=32, 3 routing iterations.
//
// Fast path: materialize priors bf16 once via MFMA (k1), layout [n][b][k][o];
// iterations 1/2 (k23) are wave-autonomous streaming passes: one wave per
// (b, 32-node chunk), lane=(k, o-half); softmax over k via shfl butterflies
// (no LDS, no barriers); software-pipelined node loads.
// Round-4 lesson: barrier-per-node k23 was latency-bound (VALUBusy 10%,
// occ 19%, 120 us); the fix is wave autonomy, not more bandwidth.

#define BATCH 64
#define NN    2048
#define NK    32
#define NI    16
#define NO    32

typedef __bf16 bf16x8 __attribute__((ext_vector_type(8)));
typedef float  f32x16 __attribute__((ext_vector_type(16)));

__device__ __forceinline__ unsigned short f2bf(float f) {
    unsigned int x = __float_as_uint(f);
    unsigned int lsb = (x >> 16) & 1u;
    x += 0x7fffu + lsb;                 // RNE
    return (unsigned short)(x >> 16);
}
__device__ __forceinline__ float bflo(unsigned int u) { return __uint_as_float(u << 16); }
__device__ __forceinline__ float bfhi(unsigned int u) { return __uint_as_float(u & 0xffff0000u); }

// ---------------- fast path ----------------

// x [b][n][i] fp32 -> xT [n][b][i] bf16
__global__ __launch_bounds__(256) void xt_kernel(const float* __restrict__ xg,
                                                 unsigned short* __restrict__ xT) {
    int id = blockIdx.x * 256 + threadIdx.x;      // 524288
    int b = id >> 13;
    int rem = id & 8191;
    int n = rem >> 2;
    int i4 = rem & 3;
    float4 v = *(const float4*)(xg + ((size_t)b * NN + n) * NI + i4 * 4);
    ushort4 o;
    o.x = f2bf(v.x); o.y = f2bf(v.y); o.z = f2bf(v.z); o.w = f2bf(v.w);
    *(ushort4*)(xT + ((size_t)n * BATCH + b) * NI + i4 * 4) = o;
}

// One wave per (chunk c of 16 nodes, capsule k): 4096 tasks, 512 blocks x 8 waves.
// MFMA operands: A = W-frag (A[m=o][kd=i]), B = x-frag (B[kd=i][n=b]) so that
// D[m=o][col=b]: lane col=b, rows o=(r&3)+8*(r>>2)+4h -> 4-consecutive o runs
// => ushort4 stores into priors[n][b][k][o]. s0 accumulated in regs (1/32).
__global__ __launch_bounds__(512) void k1_kernel(
    const unsigned short* __restrict__ xT,   // bf16 [n][b][i]
    const float* __restrict__ Wg,            // fp32 [n][k][i][o]
    unsigned short* __restrict__ priors,     // bf16 [n][b][k][o]
    float* __restrict__ partial)             // fp32 [128][b][k][o]
{
    const int w    = threadIdx.x >> 6;
    const int lane = threadIdx.x & 63;
    const int task = blockIdx.x * 8 + w;     // 4096 = 128 c x 32 k
    const int k  = task & 31;
    const int c  = task >> 5;                // 0..127
    const int l5 = lane & 31;                // o-row for A-load, b-col for B-load/D
    const int h  = lane >> 5;

    float s0a[16], s0b[16];
#pragma unroll
    for (int r = 0; r < 16; ++r) { s0a[r] = 0.f; s0b[r] = 0.f; }

    for (int jj = 0; jj < 16; ++jj) {
        const int n = c * 16 + jj;
        // A-frag (W): A[m=l5(o)][kd=h*8+j] = W[n][k][h*8+j][o]
        const float* wp = Wg + ((size_t)n * NK + k) * (NI * NO) + (h * 8) * NO + l5;
        union { unsigned short u[8]; bf16x8 v; } au;
#pragma unroll
        for (int j = 0; j < 8; ++j) au.u[j] = f2bf(wp[j * NO]);
        // B-frags (x): B[kd=h*8+j][n=b] = xT[n][b][h*8+j], b = l5 and l5+32
        const bf16x8 x0 = *(const bf16x8*)(xT + (size_t)n * (BATCH * NI) + l5 * NI + h * 8);
        const bf16x8 x1 = *(const bf16x8*)(xT + (size_t)n * (BATCH * NI) + (l5 + 32) * NI + h * 8);

        f32x16 c0, c1;
#pragma unroll
        for (int r = 0; r < 16; ++r) { c0[r] = 0.f; c1[r] = 0.f; }
        c0 = __builtin_amdgcn_mfma_f32_32x32x16_bf16(au.v, x0, c0, 0, 0, 0);
        c1 = __builtin_amdgcn_mfma_f32_32x32x16_bf16(au.v, x1, c1, 0, 0, 0);

        unsigned short* p0 = priors + (((size_t)n * BATCH + l5) * NK + k) * NO;
        unsigned short* p1 = priors + (((size_t)n * BATCH + l5 + 32) * NK + k) * NO;
#pragma unroll
        for (int rg = 0; rg < 4; ++rg) {
            const int ob = 8 * rg + 4 * h;
            ushort4 s0v, s1v;
            s0v.x = f2bf(c0[4*rg+0]); s0v.y = f2bf(c0[4*rg+1]);
            s0v.z = f2bf(c0[4*rg+2]); s0v.w = f2bf(c0[4*rg+3]);
            s1v.x = f2bf(c1[4*rg+0]); s1v.y = f2bf(c1[4*rg+1]);
            s1v.z = f2bf(c1[4*rg+2]); s1v.w = f2bf(c1[4*rg+3]);
            *(ushort4*)(p0 + ob) = s0v;
            *(ushort4*)(p1 + ob) = s1v;
        }
#pragma unroll
        for (int r = 0; r < 16; ++r) { s0a[r] += c0[r]; s0b[r] += c1[r]; }
    }
    float* q0 = partial + (((size_t)c * BATCH + l5) * NK + k) * NO;
    float* q1 = partial + (((size_t)c * BATCH + l5 + 32) * NK + k) * NO;
#pragma unroll
    for (int rg = 0; rg < 4; ++rg) {
        const int ob = 8 * rg + 4 * h;
        *(float4*)(q0 + ob) = make_float4(s0a[4*rg+0] * (1.f/32.f), s0a[4*rg+1] * (1.f/32.f),
                                          s0a[4*rg+2] * (1.f/32.f), s0a[4*rg+3] * (1.f/32.f));
        *(float4*)(q1 + ob) = make_float4(s0b[4*rg+0] * (1.f/32.f), s0b[4*rg+1] * (1.f/32.f),
                                          s0b[4*rg+2] * (1.f/32.f), s0b[4*rg+3] * (1.f/32.f));
    }
}

// Iterations 1/2: one wave per (b, chunk of 32 nodes). lane = k*2 + h(o-half).
// Per node: 32B/lane contiguous tile load (2KB/wave), delta dot in regs,
// shfl_xor(1) pair-sum, softmax over k via 5+5 shfl butterflies, accumulate.
template <int PASS>
__global__ __launch_bounds__(512) void k23_kernel(
    const unsigned short* __restrict__ priors,  // bf16 [n][b][k][o]
    const float* __restrict__ outv,             // fp32 [b][k][o]
    float* __restrict__ logits0,                // fp32 [n][b][k]
    float* __restrict__ partial)                // fp32 [64][b][k][o]
{
    const int wv   = threadIdx.x >> 6;
    const int lane = threadIdx.x & 63;
    const int task = blockIdx.x * 8 + wv;       // 4096 = 64 c x 64 b
    const int b = task & 63;
    const int c = task >> 6;                    // 0..63, 32 nodes each
    const int k = lane >> 1;
    const int h = lane & 1;

    float outr[16];
    {
        const float4* op = (const float4*)(outv + ((size_t)b * NK + k) * NO + h * 16);
#pragma unroll
        for (int q = 0; q < 4; ++q) {
            float4 v = op[q];
            outr[4*q+0] = v.x; outr[4*q+1] = v.y; outr[4*q+2] = v.z; outr[4*q+3] = v.w;
        }
    }

    float sa[16];
#pragma unroll
    for (int m = 0; m < 16; ++m) sa[m] = 0.f;

    // per-node uint4 stride: 64*32*32 ushorts / 8 = 8192
    const uint4* p = (const uint4*)(priors + ((((size_t)c * 32) * BATCH + b) * NK + k) * NO + h * 16);

    union Q { uint4 q[2]; unsigned u[8]; };
    Q cur, nxt;
    cur.q[0] = p[0];
    cur.q[1] = p[1];

    for (int j = 0; j < 32; ++j) {
        const int n = c * 32 + j;
        if (j < 31) {
            nxt.q[0] = p[(size_t)(j + 1) * 8192];
            nxt.q[1] = p[(size_t)(j + 1) * 8192 + 1];
        }
        float f[16];
#pragma unroll
        for (int m = 0; m < 8; ++m) {
            f[2*m]   = bflo(cur.u[m]);
            f[2*m+1] = bfhi(cur.u[m]);
        }
        float d = 0.f;
#pragma unroll
        for (int m = 0; m < 16; ++m) d = fmaf(f[m], outr[m], d);
        d += __shfl_xor(d, 1);

        const int li = (n * BATCH + b) * NK + k;
        float l;
        if constexpr (PASS == 1) {
            l = d;
            if (h == 0) logits0[li] = d;
        } else {
            l = logits0[li] + d;
        }
        float mx = l;
#pragma unroll
        for (int mask = 2; mask < 64; mask <<= 1)
            mx = fmaxf(mx, __shfl_xor(mx, mask));
        float e = __expf(l - mx);
        float s = e;
#pragma unroll
        for (int mask = 2; mask < 64; mask <<= 1)
            s += __shfl_xor(s, mask);
        float pr = e / s;
#pragma unroll
        for (int m = 0; m < 16; ++m) sa[m] = fmaf(pr, f[m], sa[m]);

        cur = nxt;
    }

    float* wq = partial + (((size_t)c * BATCH + b) * NK + k) * NO + h * 16;
#pragma unroll
    for (int q = 0; q < 4; ++q)
        *(float4*)(wq + 4 * q) = make_float4(sa[4*q], sa[4*q+1], sa[4*q+2], sa[4*q+3]);
}

// Reduce partial chunks + squash. tid = b*1024 + k*32 + o.
template <int NCH>
__global__ __launch_bounds__(256) void reduce_squash_f(
    const float* __restrict__ partial,
    float* __restrict__ outf)
{
    const int tid = blockIdx.x * 256 + threadIdx.x;
    float v = 0.f;
    for (int cix = 0; cix < NCH; ++cix)
        v += partial[(size_t)cix * (BATCH * NK * NO) + tid];
    float sq = v * v;
#pragma unroll
    for (int off = 1; off < 32; off <<= 1)
        sq += __shfl_xor(sq, off);
    float coef = sq / ((1.f + sq) * sqrtf(sq));
    outf[tid] = v * coef;
}

// ---------------- legacy fallback (round-2 code, known-good 582 us) ----------------

#define LBB 32
#define LNCHUNK 8
#define LNBLK (NN / LNCHUNK)
#define LTHREADS 512
#define WK_STRIDE 516

template <int PASS>
__global__ __launch_bounds__(LTHREADS, 1) void legacy_pass(
    const float* __restrict__ xg, const float* __restrict__ Wg,
    const float* __restrict__ outv, float* __restrict__ logits,
    float* __restrict__ partial)
{
    __shared__ float w_lds[NK * WK_STRIDE];
    __shared__ float x_lds[LBB][NI + 1];
    __shared__ float delta_lds[LBB][NK + 1];
    const int t = threadIdx.x, nb = blockIdx.x, bg = blockIdx.y;
    const int b0 = bg * LBB;
    const int k = t >> 4, bq = t & 15, bl0 = bq * 2, bl1 = bq * 2 + 1;
    float acc0[NO], acc1[NO];
#pragma unroll
    for (int o = 0; o < NO; ++o) { acc0[o] = 0.f; acc1[o] = 0.f; }
    float outr0[NO], outr1[NO];
    if constexpr (PASS >= 1) {
        const float4* o0 = (const float4*)&outv[((b0 + bl0) * NK + k) * NO];
        const float4* o1 = (const float4*)&outv[((b0 + bl1) * NK + k) * NO];
#pragma unroll
        for (int q = 0; q < NO / 4; ++q) {
            float4 a = o0[q]; float4 b = o1[q];
            outr0[4*q+0]=a.x; outr0[4*q+1]=a.y; outr0[4*q+2]=a.z; outr0[4*q+3]=a.w;
            outr1[4*q+0]=b.x; outr1[4*q+1]=b.y; outr1[4*q+2]=b.z; outr1[4*q+3]=b.w;
        }
    }
    for (int j = 0; j < LNCHUNK; ++j) {
        const int n = nb * LNCHUNK + j;
        __syncthreads();
        {
            const float4* src = (const float4*)(Wg + (size_t)n * (NK * NI * NO));
#pragma unroll
            for (int r = 0; r < (NK * NI * NO / 4) / LTHREADS; ++r) {
                int idx4 = t + r * LTHREADS;
                float4 v = src[idx4];
                int e = idx4 * 4, kk = e >> 9, rem = e & 511;
                *(float4*)&w_lds[kk * WK_STRIDE + rem] = v;
            }
        }
        { int bl = t >> 4, i = t & 15;
          x_lds[bl][i] = xg[((size_t)(b0 + bl) * NN + n) * NI + i]; }
        __syncthreads();
        if constexpr (PASS == 0) {
#pragma unroll
            for (int i = 0; i < NI; ++i) {
                float xa = x_lds[bl0][i], xb = x_lds[bl1][i];
                const float* wrow = &w_lds[k * WK_STRIDE + i * NO];
#pragma unroll
                for (int o = 0; o < NO; ++o) {
                    float w = wrow[o];
                    acc0[o] = fmaf(xa, w, acc0[o]);
                    acc1[o] = fmaf(xb, w, acc1[o]);
                }
            }
        } else {
            float pr0[NO], pr1[NO];
#pragma unroll
            for (int o = 0; o < NO; ++o) { pr0[o] = 0.f; pr1[o] = 0.f; }
#pragma unroll
            for (int i = 0; i < NI; ++i) {
                float xa = x_lds[bl0][i], xb = x_lds[bl1][i];
                const float* wrow = &w_lds[k * WK_STRIDE + i * NO];
#pragma unroll
                for (int o = 0; o < NO; ++o) {
                    float w = wrow[o];
                    pr0[o] = fmaf(xa, w, pr0[o]);
                    pr1[o] = fmaf(xb, w, pr1[o]);
                }
            }
            float d0 = 0.f, d1 = 0.f;
#pragma unroll
            for (int o = 0; o < NO; ++o) {
                d0 = fmaf(pr0[o], outr0[o], d0);
                d1 = fmaf(pr1[o], outr1[o], d1);
            }
            float l0 = d0, l1 = d1;
            const size_t li0 = ((size_t)(b0 + bl0) * NN + n) * NK + k;
            const size_t li1 = ((size_t)(b0 + bl1) * NN + n) * NK + k;
            if constexpr (PASS == 2) { l0 += logits[li0]; l1 += logits[li1]; }
            else { logits[li0] = d0; logits[li1] = d1; }
            delta_lds[bl0][k] = l0; delta_lds[bl1][k] = l1;
            __syncthreads();
            float m0 = -1e30f, m1 = -1e30f;
#pragma unroll
            for (int kk = 0; kk < NK; ++kk) {
                m0 = fmaxf(m0, delta_lds[bl0][kk]);
                m1 = fmaxf(m1, delta_lds[bl1][kk]);
            }
            float s0 = 0.f, s1 = 0.f;
#pragma unroll
            for (int kk = 0; kk < NK; ++kk) {
                s0 += __expf(delta_lds[bl0][kk] - m0);
                s1 += __expf(delta_lds[bl1][kk] - m1);
            }
            float p0 = __expf(l0 - m0) / s0;
            float p1 = __expf(l1 - m1) / s1;
#pragma unroll
            for (int o = 0; o < NO; ++o) {
                acc0[o] = fmaf(p0, pr0[o], acc0[o]);
                acc1[o] = fmaf(p1, pr1[o], acc1[o]);
            }
        }
    }
    const float scale = (PASS == 0) ? (1.f / NK) : 1.f;
    float4* p0 = (float4*)&partial[(((size_t)nb * BATCH + (b0 + bl0)) * NK + k) * NO];
    float4* p1 = (float4*)&partial[(((size_t)nb * BATCH + (b0 + bl1)) * NK + k) * NO];
#pragma unroll
    for (int q = 0; q < NO / 4; ++q) {
        float4 v0, v1;
        v0.x = acc0[4*q+0]*scale; v0.y = acc0[4*q+1]*scale;
        v0.z = acc0[4*q+2]*scale; v0.w = acc0[4*q+3]*scale;
        v1.x = acc1[4*q+0]*scale; v1.y = acc1[4*q+1]*scale;
        v1.z = acc1[4*q+2]*scale; v1.w = acc1[4*q+3]*scale;
        p0[q] = v0; p1[q] = v1;
    }
}

__global__ __launch_bounds__(256) void legacy_reduce(
    const float* __restrict__ partial, float* __restrict__ outf)
{
    const int tid = blockIdx.x * 256 + threadIdx.x;
    float v = 0.f;
    for (int nb = 0; nb < LNBLK; ++nb)
        v += partial[(size_t)nb * (BATCH * NK * NO) + tid];
    float sq = v * v;
#pragma unroll
    for (int off = 1; off < 32; off <<= 1) sq += __shfl_xor(sq, off);
    float coef = sq / ((1.f + sq) * sqrtf(sq));
    outf[tid] = v * coef;
}

// ---------------- launch ----------------

extern "C" void kernel_launch(void* const* d_in, const int* in_sizes, int n_in,
                              void* d_out, int out_size, void* d_ws, size_t ws_size,
                              hipStream_t stream)
{
    const float* xg = (const float*)d_in[0];
    const float* Wg = (const float*)d_in[1];
    float* outp = (float*)d_out;
    char* ws = (char*)d_ws;

    const size_t SZ_PRIORS  = (size_t)NN * BATCH * NK * NO * 2;      // 256 MiB
    const size_t SZ_PARTIAL = (size_t)128 * BATCH * NK * NO * 4;     //  32 MiB
    const size_t SZ_LOGITS  = (size_t)NN * BATCH * NK * 4;           //  16 MiB
    const size_t SZ_XT      = (size_t)NN * BATCH * NI * 2;           //   4 MiB
    const size_t SZ_OUTV    = (size_t)BATCH * NK * NO * 4;           // 256 KiB
    const size_t NEED = SZ_PRIORS + SZ_PARTIAL + SZ_LOGITS + SZ_XT + SZ_OUTV;

    if (ws_size >= NEED) {
        unsigned short* priors = (unsigned short*)ws;
        float* partial = (float*)(ws + SZ_PRIORS);
        float* logits0 = (float*)(ws + SZ_PRIORS + SZ_PARTIAL);
        unsigned short* xT = (unsigned short*)(ws + SZ_PRIORS + SZ_PARTIAL + SZ_LOGITS);
        float* outv = (float*)(ws + SZ_PRIORS + SZ_PARTIAL + SZ_LOGITS + SZ_XT);

        xt_kernel<<<2048, 256, 0, stream>>>(xg, xT);
        k1_kernel<<<512, 512, 0, stream>>>(xT, Wg, priors, partial);
        reduce_squash_f<128><<<256, 256, 0, stream>>>(partial, outv);
        k23_kernel<1><<<512, 512, 0, stream>>>(priors, outv, logits0, partial);
        reduce_squash_f<64><<<256, 256, 0, stream>>>(partial, outv);
        k23_kernel<2><<<512, 512, 0, stream>>>(priors, outv, logits0, partial);
        reduce_squash_f<64><<<256, 256, 0, stream>>>(partial, outp);
    } else {
        float* partial = (float*)ws;
        float* logits = (float*)(ws + (size_t)LNBLK * BATCH * NK * NO * 4);
        float* outv = (float*)(ws + (size_t)LNBLK * BATCH * NK * NO * 4 + (size_t)BATCH * NN * NK * 4);
        dim3 grid(LNBLK, BATCH / LBB);
        const int rblocks = BATCH * NK * NO / 256;
        legacy_pass<0><<<grid, LTHREADS, 0, stream>>>(xg, Wg, nullptr, logits, partial);
        legacy_reduce<<<rblocks, 256, 0, stream>>>(partial, outv);
        legacy_pass<1><<<grid, LTHREADS, 0, stream>>>(xg, Wg, outv, logits, partial);
        legacy_reduce<<<rblocks, 256, 0, stream>>>(partial, outv);
        legacy_pass<2><<<grid, LTHREADS, 0, stream>>>(xg, Wg, outv, logits, partial);
        legacy_reduce<<<rblocks, 256, 0, stream>>>(partial, outp);
    }
}